// Round 6
// baseline (253.136 us; speedup 1.0000x reference)
//
#include <hip/hip_runtime.h>

#define SIG 2.8853900817779268f           // 2 * log2(e)
#define INV_SIG3 (1.0f/(SIG*SIG*SIG))

__device__ __forceinline__ float rcp_f (float x){ return __builtin_amdgcn_rcpf(x);  }
__device__ __forceinline__ float exp2_f(float x){ return __builtin_amdgcn_exp2f(x); }

// One full sigmoid-batch for radix r=RR with powers (SPC,SPD) and true-product MULT.
// mulnn = C2 - 2*sum_k W2[k]*sigma(t_k); quads of 4 sigmoids share one rcp.
#define SBODY(SPC, SPD, MULT, RR) do {                                                  \
    const float* frow_ = fW1 + ((RR) << 4);    /* wave-uniform -> s_load */             \
    float s2_ = 0.f;                                                                    \
    _Pragma("unroll")                                                                   \
    for (int qd_ = 0; qd_ < 4; ++qd_) {                                                 \
        const int k0_ = qd_ * 4;                                                        \
        const float t0_ = fmaf((SPD), W1[8*16+k0_+0], fmaf((SPC), W1[7*16+k0_+0], AB[k0_+0])); \
        const float t1_ = fmaf((SPD), W1[8*16+k0_+1], fmaf((SPC), W1[7*16+k0_+1], AB[k0_+1])); \
        const float t2_ = fmaf((SPD), W1[8*16+k0_+2], fmaf((SPC), W1[7*16+k0_+2], AB[k0_+2])); \
        const float t3_ = fmaf((SPD), W1[8*16+k0_+3], fmaf((SPC), W1[7*16+k0_+3], AB[k0_+3])); \
        const float e0_ = exp2_f(t0_) + 1.f;                                            \
        const float e1_ = exp2_f(t1_) + 1.f;                                            \
        const float e2_ = exp2_f(t2_) + 1.f;                                            \
        const float e3_ = exp2_f(t3_) + 1.f;                                            \
        const float n01_ = fmaf(W2[k0_+1], e0_, W2[k0_+0] * e1_);                       \
        const float d01_ = e0_ * e1_;                                                   \
        const float n23_ = fmaf(W2[k0_+3], e2_, W2[k0_+2] * e3_);                       \
        const float d23_ = e2_ * e3_;                                                   \
        const float Nq_  = fmaf(n01_, d23_, n23_ * d01_);                               \
        const float Dq_  = d01_ * d23_;                                                 \
        s2_ = fmaf(Nq_, rcp_f(Dq_), s2_);                                               \
    }                                                                                   \
    const float mulnn_ = fmaf(-2.f, s2_, C2);                                           \
    Lsum += fabsf((MULT) - mulnn_);                                                     \
    _Pragma("unroll")                                                                   \
    for (int k_ = 0; k_ < 16; ++k_) acc[k_] = fmaf(mulnn_, frow_[k_], acc[k_]);         \
} while (0)

// Block: 448 threads = 7 waves; wave s handles permutation s for 64 consecutive m.
__global__ __launch_bounds__(448) void maron_kernel(
    const float* __restrict__ x,      // (64,14,1024)
    const float* __restrict__ W1,     // (14,16)
    const float* __restrict__ b1,     // (16)
    const float* __restrict__ W2,     // (16,1)
    const float* __restrict__ b2p,    // (1)
    const float* __restrict__ fW1,    // (120,16)
    const float* __restrict__ fb1,    // (16)
    const float* __restrict__ fW2,    // (16,1)
    const float* __restrict__ fb2p,   // (1)
    float* __restrict__ out,          // (M) out ++ (M) L
    int M)
{
    __shared__ float red[7][64][17];  // stride 17 (odd) -> conflict-free

    const int tid = threadIdx.x;
    const int s   = tid >> 6;         // 0..6 (wave-uniform)
    const int ml  = tid & 63;
    const int m   = blockIdx.x * 64 + ml;
    const int bb  = m >> 10, tt = m & 1023;

    const float* xb = x + (size_t)bb * 14 * 1024 + tt;
    const int i0 = (7 - s) % 7;
    const int i1 = (8 - s) % 7;

    const float u = xb[(i0    ) * 1024];
    const float v = xb[(i1    ) * 1024];
    const float w = xb[(7 + i0) * 1024];
    float z = fmaxf(xb[(7 + i1) * 1024], 3.814697265625e-6f);  // 2^-18
    const float rz  = rcp_f(z);
    const float w2  = w * w;
    const float rz2 = rz * rz;
    const float wz  = w * rz;
    const float wz2 = wz * wz;

    // C2 = b2 + sum W2 (wave-uniform)
    float C2 = b2p[0];
#pragma unroll
    for (int k = 0; k < 16; ++k) C2 += W2[k];

    // AB[k] = SIG*(b1 + sum_{j!=7,8} W1[j,k]*p_j), evolved incrementally; a=b=0 init.
    float AB[16];
#pragma unroll
    for (int k = 0; k < 16; ++k) {
        float t = b1[k] + W1[0*16+k] + W1[1*16+k];
        t += W1[2*16+k] + W1[3*16+k] + W1[4*16+k] + W1[5*16+k] + W1[6*16+k];
        t += W1[9*16+k] + W1[10*16+k] + W1[11*16+k] + W1[12*16+k] + W1[13*16+k];
        AB[k] = SIG * t;
    }

    float acc[16];
#pragma unroll
    for (int k = 0; k < 16; ++k) acc[k] = 0.f;
    float Lsum = 0.f;

    const float z2 = z * z, z4 = z2 * z2;
    float zna = SIG * (z4 * z2 * z);   // SIG * z^(7-a)
    float spa = SIG;                   // SIG * u^a
    float spb = SIG;                   // SIG * v^b
    float znb = zna;                   // SIG * z^(7-a-b)

    int r = 0;
    for (int a = 0; a <= 7; ++a) {
        for (int bi = 0; bi <= 7 - a; ++bi) {
            const int cmax = 7 - a - bi;
            float spc  = SIG;                            // SIG * w^c
            float spd  = znb;                            // SIG * z^d
            float mulT = ((spa * spb) * znb) * INV_SIG3; // u^a v^b w^c z^d at c=0

            int ci = 0;
            // unroll-by-2: two independent sigmoid batches in flight
            for (; ci + 1 <= cmax; ci += 2) {
                const float spcB  = spc * w;
                const float spdB  = spd * rz;
                const float mulTB = mulT * wz;
                SBODY(spc,  spd,  mulT,  r);
                SBODY(spcB, spdB, mulTB, r + 1);
                spc *= w2; spd *= rz2; mulT *= wz2;
                r += 2;
            }
            if (ci <= cmax) {
                SBODY(spc, spd, mulT, r);
                ++r;
            }

            // b -> b+1
            const float dspb = spb * (v - 1.f);
#pragma unroll
            for (int k = 0; k < 16; ++k) AB[k] = fmaf(dspb, W1[1*16+k], AB[k]);
            spb *= v;
            znb *= rz;
        }
        // a -> a+1 (and reset b-contribution to SIG)
        const float dspa = spa * (u - 1.f);
        const float dB   = SIG - spb;
#pragma unroll
        for (int k = 0; k < 16; ++k)
            AB[k] = fmaf(dspa, W1[0*16+k], fmaf(dB, W1[1*16+k], AB[k]));
        spa *= u;
        zna *= rz;
        spb = SIG;
        znb = zna;
    }

#pragma unroll
    for (int k = 0; k < 16; ++k) red[s][ml][k] = acc[k];
    red[s][ml][16] = Lsum;
    __syncthreads();

    // parallel 7-way reduction: 64*17 = 1088 (m,k) slots over 448 threads
    for (int p = tid; p < 64 * 17; p += 448) {
        const int kk = p >> 6;       // 0..16
        const int mm = p & 63;
        float t = red[0][mm][kk];
#pragma unroll
        for (int ss = 1; ss < 7; ++ss) t += red[ss][mm][kk];
        red[0][mm][kk] = t;          // each (mm,kk) owned by exactly one thread
    }
    __syncthreads();

    if (tid < 64) {
        float o = fb2p[0];
        float s3 = 0.f;
#pragma unroll
        for (int k = 0; k < 16; ++k) {
            const float a2 = SIG * (red[0][tid][k] + fb1[k]);
            const float rk = rcp_f(exp2_f(a2) + 1.f);
            s3 = fmaf(fW2[k], rk, s3);
            o += fW2[k];
        }
        o = fmaf(-2.f, s3, o);

        const int mo = blockIdx.x * 64 + tid;
        out[mo]     = o;
        out[M + mo] = red[0][tid][16] * (1.f / 120.f);
    }
}

extern "C" void kernel_launch(void* const* d_in, const int* in_sizes, int n_in,
                              void* d_out, int out_size, void* d_ws, size_t ws_size,
                              hipStream_t stream) {
    const float* x   = (const float*)d_in[0];
    const float* W1  = (const float*)d_in[1];
    const float* b1  = (const float*)d_in[2];
    const float* W2  = (const float*)d_in[3];
    const float* b2  = (const float*)d_in[4];
    const float* fW1 = (const float*)d_in[5];
    const float* fb1 = (const float*)d_in[6];
    const float* fW2 = (const float*)d_in[7];
    const float* fb2 = (const float*)d_in[8];

    const int M = out_size / 2;           // 65536
    const int blocks = M / 64;            // 1024

    maron_kernel<<<blocks, 448, 0, stream>>>(x, W1, b1, W2, b2, fW1, fb1, fW2, fb2,
                                             (float*)d_out, M);
}